// Round 7
// baseline (3460.654 us; speedup 1.0000x reference)
//
#include <hip/hip_runtime.h>
#include <hip/hip_bf16.h>
#include <stdint.h>

// GRU decoder: B=128, IN=256, H=512, SEQ=1024, fp32 out.
// R7: 8 bg x 32 hg = 256 one-wave WGs (16 rows x 16 cols each).
// - w_hh bf16 fragments in LDS (48 KB, staged once).
// - h exchange buffer stored in A-FRAGMENT ORDER: consumer reads are 16
//   fully-coalesced 1 KB wave loads; producer owns a contiguous 512 B region
//   (packed via shfl_xor, no LDS).
// - step tail reordered: h stores -> vmcnt(0) -> flag -> out stores -> poll,
//   so the fp32 HBM out-store drain overlaps the poll instead of the flag.
// - sync: relaxed system-scope (cache-bypassing) atomics only; no acquire-inv,
//   no wbl2, no RMW contention.

constexpr int SEQ = 1024;
constexpr int BATCH = 128;
constexpr int IND = 256;
constexpr int HD = 512;
constexpr int BG = 8;
constexpr int HG = 32;
constexpr int ROWS = BATCH / BG;   // 16
constexpr int NT = 3;              // gate tiles: r, z, n

using frag16 = __attribute__((ext_vector_type(8))) short;  // 8 bf16
using f32x4  = __attribute__((ext_vector_type(4))) float;

// ws layout (bytes): hx = 2 parity bufs * BG * 16 KB, then flags
constexpr size_t HX_BUF_ULL = (size_t)BG * 2048;           // ulls per parity buffer
constexpr size_t WS_FLAGS   = 2 * HX_BUF_ULL * 8;          // byte offset of flags

__device__ __forceinline__ float sigmoid_f(float x) {
    return 1.f / (1.f + __expf(-x));
}
__device__ __forceinline__ float tanh_f(float x) {
    float e = __expf(2.f * x);
    return 1.f - 2.f / (e + 1.f);
}
__device__ __forceinline__ unsigned short f2bfu(float x) {
    return __bfloat16_as_ushort(__float2bfloat16(x));
}

__global__ __launch_bounds__(64) void gru_kernel(
    const float* __restrict__ x,      // [128, 256]
    const float* __restrict__ w_ih,   // [1536, 256]
    const float* __restrict__ w_hh,   // [1536, 512]
    const float* __restrict__ b_ih,   // [1536]
    const float* __restrict__ b_hh,   // [1536]
    unsigned long long* __restrict__ hx,  // 2 * BG * 2048 ull (frag-order h)
    unsigned* __restrict__ flags,         // [BG*HG]
    float* __restrict__ out)              // [128, 1024, 512] fp32
{
    const int lane = threadIdx.x;
    const int bg = blockIdx.x & 7;
    const int hg = blockIdx.x >> 3;
    const int b0 = bg * ROWS;
    const int c0 = hg * 16;
    const int nlo = lane & 15;
    const int quad = lane >> 4;

    int gcol[NT];
    gcol[0] = c0 + nlo;           // r
    gcol[1] = HD + c0 + nlo;      // z
    gcol[2] = 2 * HD + c0 + nlo;  // n

    // ---- stage w_hh slice -> LDS in fragment order (once) ----
    __shared__ frag16 ldsB[NT * 16 * 64];  // 48 KB
#pragma unroll
    for (int t = 0; t < NT; ++t) {
        for (int kc = 0; kc < 16; ++kc) {
            const float* src = w_hh + (size_t)gcol[t] * HD + kc * 32 + quad * 8;
            float4 v0 = *(const float4*)src;
            float4 v1 = *(const float4*)(src + 4);
            frag16 f;
            f[0] = (short)f2bfu(v0.x); f[1] = (short)f2bfu(v0.y);
            f[2] = (short)f2bfu(v0.z); f[3] = (short)f2bfu(v0.w);
            f[4] = (short)f2bfu(v1.x); f[5] = (short)f2bfu(v1.y);
            f[6] = (short)f2bfu(v1.z); f[7] = (short)f2bfu(v1.w);
            ldsB[(t * 16 + kc) * 64 + lane] = f;
        }
    }

    // ---- gi = x @ w_ih.T + b_ih (+ b_hh folded for r,z) ----
    float gi[NT][4];
    float bhn = b_hh[gcol[2]];
#pragma unroll
    for (int t = 0; t < NT; ++t) {
        float bi = b_ih[gcol[t]] + ((t < 2) ? b_hh[gcol[t]] : 0.f);
#pragma unroll
        for (int r = 0; r < 4; ++r) gi[t][r] = bi;
    }
    for (int r = 0; r < 4; ++r) {
        const float4* xr = (const float4*)(x + (size_t)(b0 + quad * 4 + r) * IND);
        for (int kc = 0; kc < IND / 4; ++kc) {
            float4 xv = xr[kc];
#pragma unroll
            for (int t = 0; t < NT; ++t) {
                float4 wv = ((const float4*)(w_ih + (size_t)gcol[t] * IND))[kc];
                gi[t][r] += xv.x * wv.x + xv.y * wv.y + xv.z * wv.z + xv.w * wv.w;
            }
        }
    }

    // ---- recurrence ----
    float hreg[4];
#pragma unroll
    for (int r = 0; r < 4; ++r) hreg[r] = 0.f;

    unsigned* myflag = flags + bg * HG + hg;
    unsigned* pollflag = flags + bg * HG + (lane & 31);

    for (int s = 0; s < SEQ; ++s) {
        f32x4 C[NT];
#pragma unroll
        for (int t = 0; t < NT; ++t) C[t] = (f32x4){0.f, 0.f, 0.f, 0.f};

        if (s > 0) {
            // coalesced frag-order loads: lane's A-frag for chunk kc is at
            // hx[parity][bg] + kc*128 + lane*2 (ull)
            const unsigned long long* hb =
                hx + ((size_t)(s & 1) * BG + bg) * 2048 + (size_t)lane * 2;
            unsigned long long a0[16], a1[16];
#pragma unroll
            for (int kc = 0; kc < 16; ++kc) {
                a0[kc] = __hip_atomic_load(hb + kc * 128,     __ATOMIC_RELAXED, __HIP_MEMORY_SCOPE_SYSTEM);
                a1[kc] = __hip_atomic_load(hb + kc * 128 + 1, __ATOMIC_RELAXED, __HIP_MEMORY_SCOPE_SYSTEM);
            }
#pragma unroll
            for (int kc = 0; kc < 16; ++kc) {
                union { unsigned long long u[2]; frag16 f; } af;
                af.u[0] = a0[kc];
                af.u[1] = a1[kc];
#pragma unroll
                for (int t = 0; t < NT; ++t) {
                    frag16 bfr = ldsB[(t * 16 + kc) * 64 + lane];
                    C[t] = __builtin_amdgcn_mfma_f32_16x16x32_bf16(af.f, bfr, C[t], 0, 0, 0);
                }
            }
        }

        unsigned long long* hw = hx + ((size_t)((s + 1) & 1) * BG + bg) * 2048;
        float ov[4];
#pragma unroll
        for (int r = 0; r < 4; ++r) {
            float gr  = gi[0][r] + C[0][r];
            float gz  = gi[1][r] + C[1][r];
            float ghn = C[2][r] + bhn;
            float rr = sigmoid_f(gr);
            float zz = sigmoid_f(gz);
            float nn = tanh_f(gi[2][r] + rr * ghn);
            float hn = (1.f - zz) * nn + zz * hreg[r];
            hreg[r] = hn;
            ov[r] = hn;
            // pack 8 cols (one chunk) into lanes nlo%8==0 via shfl_xor tree
            unsigned own = (unsigned)f2bfu(hn);
            unsigned v0 = own | ((unsigned)__shfl_xor((int)own, 1) << 16); // cols nlo..nlo+1
            unsigned w1 = (unsigned)__shfl_xor((int)v0, 2);                // cols nlo+2..+3
            unsigned u2 = (unsigned)__shfl_xor((int)v0, 4);                // cols nlo+4..+5
            unsigned u3 = (unsigned)__shfl_xor((int)w1, 4);                // cols nlo+6..+7
            if ((lane & 7) == 0) {
                unsigned long long lo = (unsigned long long)v0 | ((unsigned long long)w1 << 32);
                unsigned long long hi = (unsigned long long)u2 | ((unsigned long long)u3 << 32);
                // chunk (row n = quad*4+r, col-half c = nlo>>3) -> hg*64 + c*32 + n*2
                size_t ci = (size_t)hg * 64 + (size_t)(nlo >> 3) * 32 + (size_t)(quad * 4 + r) * 2;
                __hip_atomic_store(hw + ci,     lo, __ATOMIC_RELAXED, __HIP_MEMORY_SCOPE_SYSTEM);
                __hip_atomic_store(hw + ci + 1, hi, __ATOMIC_RELAXED, __HIP_MEMORY_SCOPE_SYSTEM);
            }
        }

        if (s < SEQ - 1) {
            // drain h stores only (out stores from last step are long done)
            asm volatile("s_waitcnt vmcnt(0)" ::: "memory");
            if (lane == 0)
                __hip_atomic_store(myflag, (unsigned)(s + 1),
                                   __ATOMIC_RELAXED, __HIP_MEMORY_SCOPE_SYSTEM);
            asm volatile("" ::: "memory");
        }

        // out stores AFTER flag publish: HBM write-ack overlaps the poll
        {
            float* op = out + (size_t)(b0 + quad * 4) * (SEQ * HD) + (size_t)s * HD + c0 + nlo;
#pragma unroll
            for (int r = 0; r < 4; ++r)
                op[(size_t)r * (SEQ * HD)] = ov[r];
        }

        if (s < SEQ - 1) {
            asm volatile("" ::: "memory");
            bool done = false;
            do {
                unsigned v = __hip_atomic_load(pollflag, __ATOMIC_RELAXED,
                                               __HIP_MEMORY_SCOPE_SYSTEM);
                done = (__ballot(v > (unsigned)s) == ~0ull);
            } while (!done);
            asm volatile("" ::: "memory");
        }
    }
}

extern "C" void kernel_launch(void* const* d_in, const int* in_sizes, int n_in,
                              void* d_out, int out_size, void* d_ws, size_t ws_size,
                              hipStream_t stream) {
    (void)in_sizes; (void)n_in; (void)out_size; (void)ws_size;
    const float* x    = (const float*)d_in[0];
    const float* w_ih = (const float*)d_in[1];
    const float* w_hh = (const float*)d_in[2];
    const float* b_ih = (const float*)d_in[3];
    const float* b_hh = (const float*)d_in[4];

    char* ws = (char*)d_ws;
    unsigned long long* hx = (unsigned long long*)ws;
    unsigned* flags = (unsigned*)(ws + WS_FLAGS);

    hipMemsetAsync(flags, 0, (size_t)BG * HG * sizeof(unsigned), stream);
    gru_kernel<<<BG * HG, 64, 0, stream>>>(x, w_ih, w_hh, b_ih, b_hh, hx, flags,
                                           (float*)d_out);
}